// Round 1
// baseline (922.254 us; speedup 1.0000x reference)
//
#include <hip/hip_runtime.h>
#include <math.h>

// ---------------------------------------------------------------------------
// VAE ELBO (chromatin VAE). Sizes are fixed by the reference.
//
// Key restructurings vs the JAX graph:
//  * NB_ENC == NB_DEC == 16 with identical binning => ONE histogram
//    hist[(g*16+b)*1024 + c] serves both the encoder input (x = log1p(counts))
//    and the mixture likelihood:
//      sum_cuts lm = sum_{c,g,k} hist * (logits[k]-lse) + N_CUTS*log(16)
//    This removes the 4M x 16-float gather and the 65MB mixture_delta tensor.
//  * enc_b1 cancels exactly through BatchNorm (per-feature mean subtract).
//  * Decoder fused per (cell,gene): gene-per-block => logit_weight reads are
//    wave-uniform (scalar loads); latent stored transposed [l][c] for
//    coalesced vector loads; fragcounts transposed [g][c].
//  * Everything accumulates (pre-scaled, pre-signed) into one f64 accumulator.
// ---------------------------------------------------------------------------

#define G_      1000
#define C_      1024
#define L_      50
#define K_      16
#define NIN_    (G_ * K_)          // 16000 encoder input bins per cell
#define NHID_   16
#define NCUTS_  4000000
#define NFRAGS_ 2000000
#define CUT_SCALE   12.5f          // N_TOTAL_CUTS / N_CUTS
#define CELL_SCALE  9.765625f      // N_TOTAL_CELLS / N_CELLS

// ws layout (bytes); all 8-aligned
#define HIST_OFF 0ull              // u32 [16000][1024]  (i=(g*16+b), c)
#define FRAG_OFF 65536000ull       // u32 [1000][1024]   (g, c)
#define H_OFF    69632000ull       // f32 [1024][16]     raw encoder h (no b1)
#define BN_OFF   69697536ull       // f32 scale[16], shift[16]
#define LATT_OFF 69697664ull       // f32 [50][1024]     latent transposed
#define ACC_OFF  69902464ull       // f64 [1]
#define WS_BYTES 69902472ull

__device__ __forceinline__ float block_sum_256(float v) {
    __shared__ float sm[256];
    int t = threadIdx.x;
    __syncthreads();
    sm[t] = v;
    __syncthreads();
#pragma unroll
    for (int s = 128; s > 0; s >>= 1) {
        if (t < s) sm[t] += sm[t + s];
        __syncthreads();
    }
    return sm[0];
}

// --- 1. cut histogram: hist[(g*16+b)*1024 + c] += 1 ------------------------
__global__ void hist_kernel(const float* __restrict__ coord,
                            const int* __restrict__ cxg,
                            unsigned int* __restrict__ hist, int n) {
    int i = blockIdx.x * 256 + threadIdx.x;
    if (i >= n) return;
    float x = coord[i];
    int b = (int)(x * 16.0f);
    b = b > 15 ? 15 : b;
    int ix = cxg[i];
    int c = ix / G_;
    int g = ix - c * G_;
    atomicAdd(&hist[(size_t)(g * K_ + b) * C_ + c], 1u);
}

// --- 2. fragment counts (transposed [g][c]) --------------------------------
__global__ void frag_kernel(const int* __restrict__ fix,
                            unsigned int* __restrict__ frag, int n) {
    int i = blockIdx.x * 256 + threadIdx.x;
    if (i >= n) return;
    int ix = fix[i];
    int c = ix / G_;
    int g = ix - c * G_;
    atomicAdd(&frag[(size_t)g * C_ + c], 1u);
}

// --- 3. encoder matmul: h[c][j] = sum_i log1p(hist[i][c]) * W1[i][j] -------
// grid (4 cell-tiles, 16 i-chunks) x 256 threads; thread = one cell in tile.
__global__ __launch_bounds__(256)
void enc_kernel(const unsigned int* __restrict__ hist,
                const float* __restrict__ W1,   // [16000][16]
                float* __restrict__ h) {
    int c = blockIdx.x * 256 + threadIdx.x;
    int i0 = blockIdx.y * 1000;
    float acc[NHID_];
#pragma unroll
    for (int j = 0; j < NHID_; ++j) acc[j] = 0.f;
    for (int i = i0; i < i0 + 1000; ++i) {
        unsigned int cnt = hist[(size_t)i * C_ + c];
        float xv = log1pf((float)cnt);
        const float* w = W1 + (size_t)i * NHID_;   // wave-uniform -> s_load
#pragma unroll
        for (int j = 0; j < NHID_; ++j) acc[j] = fmaf(xv, w[j], acc[j]);
    }
#pragma unroll
    for (int j = 0; j < NHID_; ++j) atomicAdd(&h[c * NHID_ + j], acc[j]);
}

// --- 4. BN stats -> per-feature scale/shift --------------------------------
__global__ void bn_kernel(const float* __restrict__ h,
                          const float* __restrict__ gamma,
                          const float* __restrict__ beta,
                          float* __restrict__ bn) {  // bn[0..15]=scale, [16..31]=shift
    int j = blockIdx.x;
    float s1 = 0.f, s2 = 0.f;
    for (int c = threadIdx.x; c < C_; c += 256) {
        float v = h[c * NHID_ + j];
        s1 += v; s2 += v * v;
    }
    s1 = block_sum_256(s1);
    s2 = block_sum_256(s2);
    if (threadIdx.x == 0) {
        float mean = s1 * (1.0f / C_);
        float var = s2 * (1.0f / C_) - mean * mean;
        float rstd = rsqrtf(var + 1e-5f);
        float sc = gamma[j] * rstd;
        bn[j] = sc;
        bn[NHID_ + j] = beta[j] - mean * sc;
    }
}

// --- 5. latent sample + latent KL ------------------------------------------
__global__ __launch_bounds__(256)
void latent_kernel(const float* __restrict__ h,
                   const float* __restrict__ bn,
                   const float* __restrict__ W_loc,   // [16][50]
                   const float* __restrict__ b_loc,
                   const float* __restrict__ W_scale, // [16][50]
                   const float* __restrict__ b_scale,
                   const float* __restrict__ eps,     // [1024][50]
                   float* __restrict__ latT,          // [50][1024]
                   double* __restrict__ acc) {
    int idx = blockIdx.x * 256 + threadIdx.x;
    float kl = 0.f;
    if (idx < C_ * L_) {
        int c = idx / L_;
        int l = idx - c * L_;
        float hb[NHID_];
#pragma unroll
        for (int j = 0; j < NHID_; ++j) {
            float v = fmaf(h[c * NHID_ + j], bn[j], bn[NHID_ + j]);
            hb[j] = v > 0.f ? v : 0.f;
        }
        float loc = b_loc[l], ls = b_scale[l];
#pragma unroll
        for (int j = 0; j < NHID_; ++j) {
            loc = fmaf(hb[j], W_loc[j * L_ + l], loc);
            ls  = fmaf(hb[j], W_scale[j * L_ + l], ls);
        }
        float qs = 0.1f * expf(ls);
        float e = eps[idx];
        float lat = fmaf(qs, e, loc);
        latT[(size_t)l * C_ + c] = lat;
        float z = (lat - loc) / qs;
        // logN(lat;0,1) - logN(lat;loc,qs) = -lat^2/2 + z^2/2 + log(qs)
        kl = fmaf(-0.5f * lat, lat, fmaf(0.5f * z, z, logf(qs)));
    }
    float s = block_sum_256(kl);
    if (threadIdx.x == 0) atomicAdd(acc, -(double)(CELL_SCALE * s));
}

// --- 6. weight KL (logit_weight + rho_weight), N(0,0.1) --------------------
__global__ __launch_bounds__(256)
void wkl_kernel(const float* __restrict__ lw,  // 800000
                const float* __restrict__ rw,  // 50000
                double* __restrict__ acc) {
    const int NTOT = G_ * L_ * K_ + G_ * L_;   // 850000
    float s = 0.f;
    for (int i = blockIdx.x * 256 + threadIdx.x; i < NTOT; i += gridDim.x * 256) {
        float w = (i < G_ * L_ * K_) ? lw[i] : rw[i - G_ * L_ * K_];
        // -0.5*(w/0.1)^2 - log(0.1) - 0.5*log(2pi)
        s += fmaf(-50.f * w, w, 1.3836465597893733f);
    }
    s = block_sum_256(s);
    if (threadIdx.x == 0) atomicAdd(acc, -(double)s);
}

// --- 7. fused decoder: mixture + Poisson likelihood per (c,g) --------------
// grid (1000 genes, 4 cell-tiles) x 256 threads
__global__ __launch_bounds__(256)
void main_kernel(const float* __restrict__ latT,      // [50][1024]
                 const unsigned int* __restrict__ hist,
                 const unsigned int* __restrict__ frag,
                 const float* __restrict__ lw,        // [1000][50][16]
                 const float* __restrict__ rw,        // [1000][50]
                 const float* __restrict__ baseline,  // [1000][16]
                 const float* __restrict__ rho_bias,  // [1000]
                 const int* __restrict__ libsize,
                 double* __restrict__ acc) {
    int g = blockIdx.x;
    int c = blockIdx.y * 256 + threadIdx.x;
    const float* lwg = lw + (size_t)g * (L_ * K_);   // wave-uniform base
    const float* rwg = rw + (size_t)g * L_;
    float logits[K_];
#pragma unroll
    for (int k = 0; k < K_; ++k) logits[k] = baseline[g * K_ + k];
    float rho = 0.f;
    for (int l = 0; l < L_; ++l) {
        float lv = latT[(size_t)l * C_ + c];         // coalesced
        rho = fmaf(lv, rwg[l], rho);
#pragma unroll
        for (int k = 0; k < K_; ++k)
            logits[k] = fmaf(lv, lwg[l * K_ + k], logits[k]);  // s_load operand
    }
    float m = logits[0];
#pragma unroll
    for (int k = 1; k < K_; ++k) m = fmaxf(m, logits[k]);
    float se = 0.f;
#pragma unroll
    for (int k = 0; k < K_; ++k) se += expf(logits[k] - m);
    float lse = m + logf(se);
    float mix = 0.f;
#pragma unroll
    for (int k = 0; k < K_; ++k) {
        float cnt = (float)hist[(size_t)(g * K_ + k) * C_ + c];  // coalesced
        mix = fmaf(cnt, logits[k] - lse, mix);
    }
    float fc = (float)frag[(size_t)g * C_ + c];
    float fe = rho_bias[g] * expf(rho) * (float)libsize[c];
    float lf = fmaf(fc, logf(fe), -fe) - lgammaf(fc + 1.0f);
    float v = -(CUT_SCALE * mix + CELL_SCALE * lf);
    float s = block_sum_256(v);
    if (threadIdx.x == 0) atomicAdd(acc, (double)s);
}

// --- 8. finalize -----------------------------------------------------------
__global__ void final_kernel(const double* __restrict__ acc, float* __restrict__ out) {
    // -CUT_SCALE_total * log(16): 12.5 * 4e6 * log(16)
    out[0] = (float)(acc[0] - 138629436.11198905);
}

extern "C" void kernel_launch(void* const* d_in, const int* in_sizes, int n_in,
                              void* d_out, int out_size, void* d_ws, size_t ws_size,
                              hipStream_t stream) {
    const float* cut_coord = (const float*)d_in[0];
    const float* eps       = (const float*)d_in[1];
    const float* enc_W1    = (const float*)d_in[2];
    // d_in[3] = enc_b1 : cancels through BatchNorm, unused
    const float* bn_gamma  = (const float*)d_in[4];
    const float* bn_beta   = (const float*)d_in[5];
    const float* W_loc     = (const float*)d_in[6];
    const float* b_loc     = (const float*)d_in[7];
    const float* W_scale   = (const float*)d_in[8];
    const float* b_scale   = (const float*)d_in[9];
    const float* logit_w   = (const float*)d_in[10];
    const float* rho_w     = (const float*)d_in[11];
    const float* baseline  = (const float*)d_in[12];
    const float* rho_bias  = (const float*)d_in[13];
    const int* cut_cxg     = (const int*)d_in[14];
    // d_in[15] = cut_local_gene_ix : derivable from cxg (cxg % 1000), unused
    const int* frag_ix     = (const int*)d_in[16];
    // d_in[17] genes_oi = arange, d_in[18] cells_oi = arange : identity, unused
    const int* libsize     = (const int*)d_in[19];

    char* ws = (char*)d_ws;
    unsigned int* hist = (unsigned int*)(ws + HIST_OFF);
    unsigned int* frag = (unsigned int*)(ws + FRAG_OFF);
    float* h    = (float*)(ws + H_OFF);
    float* bn   = (float*)(ws + BN_OFF);
    float* latT = (float*)(ws + LATT_OFF);
    double* acc = (double*)(ws + ACC_OFF);
    float* out  = (float*)d_out;

    int n_cuts  = in_sizes[0];
    int n_frags = in_sizes[16];

    // zero hist/frag/h/bn/latT/acc in one shot (ws is poisoned 0xAA each call)
    hipMemsetAsync(d_ws, 0, WS_BYTES, stream);

    hist_kernel<<<(n_cuts + 255) / 256, 256, 0, stream>>>(cut_coord, cut_cxg, hist, n_cuts);
    frag_kernel<<<(n_frags + 255) / 256, 256, 0, stream>>>(frag_ix, frag, n_frags);
    enc_kernel<<<dim3(4, 16), 256, 0, stream>>>(hist, enc_W1, h);
    bn_kernel<<<NHID_, 256, 0, stream>>>(h, bn_gamma, bn_beta, bn);
    latent_kernel<<<(C_ * L_ + 255) / 256, 256, 0, stream>>>(
        h, bn, W_loc, b_loc, W_scale, b_scale, eps, latT, acc);
    wkl_kernel<<<512, 256, 0, stream>>>(logit_w, rho_w, acc);
    main_kernel<<<dim3(G_, 4), 256, 0, stream>>>(
        latT, hist, frag, logit_w, rho_w, baseline, rho_bias, libsize, acc);
    final_kernel<<<1, 1, 0, stream>>>(acc, out);
}

// Round 2
// 525.022 us; speedup vs baseline: 1.7566x; 1.7566x over previous
//
#include <hip/hip_runtime.h>
#include <math.h>

// ---------------------------------------------------------------------------
// VAE ELBO (chromatin VAE). Sizes fixed by the reference.
//
// Restructurings vs the JAX graph:
//  * NB_ENC == NB_DEC == 16, identical binning => ONE histogram
//    hist[(g*16+b)*1024 + c] serves both encoder input (log1p counts) and the
//    mixture likelihood (sum_{c,g,k} hist*(logits-lse) + N_CUTS*log 16).
//  * enc_b1 cancels exactly through BatchNorm.
//  * log1p(n) for integer n == __logf(1+n) exactly (1+n exact in fp32).
//  * Encoder: 250 blocks x 256 thr, thread owns 4 cells (uint4 loads),
//    register accumulate over 64 rows, one f32 atomic per (j,cell) at end.
//  * h stored transposed [j][c] for coalesced BN reduce + enc atomics.
//  * Decoder fused per (cell,gene); gene-per-block => weights are wave-
//    uniform scalar loads; latent transposed [l][c] for coalesced loads.
//  * All sums -> one f64 accumulator; constants folded at finalize.
// ---------------------------------------------------------------------------

#define G_      1000
#define C_      1024
#define L_      50
#define K_      16
#define NHID_   16
#define CUT_SCALE   12.5f          // N_TOTAL_CUTS / N_CUTS
#define CELL_SCALE  9.765625f      // N_TOTAL_CELLS / N_CELLS

// ws layout (bytes); all 8-aligned
#define HIST_OFF 0ull              // u32 [16000][1024]  (i=(g*16+b), c)
#define FRAG_OFF 65536000ull       // u32 [1000][1024]   (g, c)
#define H_OFF    69632000ull       // f32 [16][1024]     hT (transposed, no b1)
#define BN_OFF   69697536ull       // f32 scale[16], shift[16]
#define LATT_OFF 69697664ull       // f32 [50][1024]     latent transposed
#define ACC_OFF  69902464ull       // f64 [1]
#define WS_BYTES 69902472ull

__device__ __forceinline__ float block_sum_256(float v) {
    __shared__ float sm[256];
    int t = threadIdx.x;
    __syncthreads();
    sm[t] = v;
    __syncthreads();
#pragma unroll
    for (int s = 128; s > 0; s >>= 1) {
        if (t < s) sm[t] += sm[t + s];
        __syncthreads();
    }
    return sm[0];
}

// --- 1. cut histogram: hist[(g*16+b)*1024 + c] += 1 ------------------------
__global__ void hist_kernel(const float* __restrict__ coord,
                            const int* __restrict__ cxg,
                            unsigned int* __restrict__ hist, int n) {
    int i = blockIdx.x * 256 + threadIdx.x;
    if (i >= n) return;
    float x = coord[i];
    int b = (int)(x * 16.0f);
    b = b > 15 ? 15 : b;
    int ix = cxg[i];
    int c = ix / G_;
    int g = ix - c * G_;
    atomicAdd(&hist[(size_t)(g * K_ + b) * C_ + c], 1u);
}

// --- 2. fragment counts (transposed [g][c]) --------------------------------
__global__ void frag_kernel(const int* __restrict__ fix,
                            unsigned int* __restrict__ frag, int n) {
    int i = blockIdx.x * 256 + threadIdx.x;
    if (i >= n) return;
    int ix = fix[i];
    int c = ix / G_;
    int g = ix - c * G_;
    atomicAdd(&frag[(size_t)g * C_ + c], 1u);
}

// --- 3. encoder matmul: hT[j][c] = sum_i log1p(hist[i][c]) * W1[i][j] ------
// 250 blocks (64 i-rows each) x 256 threads; thread owns cells 4t..4t+3.
__global__ __launch_bounds__(256)
void enc_kernel(const unsigned int* __restrict__ hist,
                const float* __restrict__ W1,   // [16000][16]
                float* __restrict__ hT) {       // [16][1024]
    int t = threadIdx.x;
    int i0 = blockIdx.x * 64;
    float acc[NHID_][4];
#pragma unroll
    for (int j = 0; j < NHID_; ++j)
#pragma unroll
        for (int u = 0; u < 4; ++u) acc[j][u] = 0.f;
    const uint4* hrow = (const uint4*)(hist + (size_t)i0 * C_) + t;
    const float* w = W1 + (size_t)i0 * NHID_;
    for (int ii = 0; ii < 64; ++ii) {
        uint4 cnt = hrow[ii * (C_ / 4)];
        float x0 = __logf((float)(cnt.x + 1u));
        float x1 = __logf((float)(cnt.y + 1u));
        float x2 = __logf((float)(cnt.z + 1u));
        float x3 = __logf((float)(cnt.w + 1u));
        const float* wr = w + ii * NHID_;       // wave-uniform -> s_load
#pragma unroll
        for (int j = 0; j < NHID_; ++j) {
            float wj = wr[j];
            acc[j][0] = fmaf(x0, wj, acc[j][0]);
            acc[j][1] = fmaf(x1, wj, acc[j][1]);
            acc[j][2] = fmaf(x2, wj, acc[j][2]);
            acc[j][3] = fmaf(x3, wj, acc[j][3]);
        }
    }
#pragma unroll
    for (int j = 0; j < NHID_; ++j)
#pragma unroll
        for (int u = 0; u < 4; ++u)
            atomicAdd(&hT[j * C_ + 4 * t + u], acc[j][u]);
}

// --- 4. BN stats -> per-feature scale/shift --------------------------------
__global__ void bn_kernel(const float* __restrict__ hT,
                          const float* __restrict__ gamma,
                          const float* __restrict__ beta,
                          float* __restrict__ bn) {  // [0..15]=scale, [16..31]=shift
    int j = blockIdx.x;
    float s1 = 0.f, s2 = 0.f;
    for (int c = threadIdx.x; c < C_; c += 256) {
        float v = hT[j * C_ + c];
        s1 += v; s2 += v * v;
    }
    s1 = block_sum_256(s1);
    s2 = block_sum_256(s2);
    if (threadIdx.x == 0) {
        float mean = s1 * (1.0f / C_);
        float var = s2 * (1.0f / C_) - mean * mean;
        float rstd = rsqrtf(var + 1e-5f);
        float sc = gamma[j] * rstd;
        bn[j] = sc;
        bn[NHID_ + j] = beta[j] - mean * sc;
    }
}

// --- 5. latent sample + latent KL ------------------------------------------
__global__ __launch_bounds__(256)
void latent_kernel(const float* __restrict__ hT,
                   const float* __restrict__ bn,
                   const float* __restrict__ W_loc,   // [16][50]
                   const float* __restrict__ b_loc,
                   const float* __restrict__ W_scale, // [16][50]
                   const float* __restrict__ b_scale,
                   const float* __restrict__ eps,     // [1024][50]
                   float* __restrict__ latT,          // [50][1024]
                   double* __restrict__ acc) {
    int idx = blockIdx.x * 256 + threadIdx.x;
    float kl = 0.f;
    if (idx < C_ * L_) {
        int c = idx / L_;
        int l = idx - c * L_;
        float hb[NHID_];
#pragma unroll
        for (int j = 0; j < NHID_; ++j) {
            float v = fmaf(hT[j * C_ + c], bn[j], bn[NHID_ + j]);
            hb[j] = v > 0.f ? v : 0.f;
        }
        float loc = b_loc[l], ls = b_scale[l];
#pragma unroll
        for (int j = 0; j < NHID_; ++j) {
            loc = fmaf(hb[j], W_loc[j * L_ + l], loc);
            ls  = fmaf(hb[j], W_scale[j * L_ + l], ls);
        }
        float qs = 0.1f * __expf(ls);
        float e = eps[idx];
        float lat = fmaf(qs, e, loc);
        latT[(size_t)l * C_ + c] = lat;
        float z = (lat - loc) / qs;
        // logN(lat;0,1) - logN(lat;loc,qs) = -lat^2/2 + z^2/2 + log(qs)
        kl = fmaf(-0.5f * lat, lat, fmaf(0.5f * z, z, __logf(qs)));
    }
    float s = block_sum_256(kl);
    if (threadIdx.x == 0) atomicAdd(acc, -(double)(CELL_SCALE * s));
}

// --- 6. weight KL (logit_weight + rho_weight), N(0,0.1) --------------------
__global__ __launch_bounds__(256)
void wkl_kernel(const float* __restrict__ lw,  // 800000
                const float* __restrict__ rw,  // 50000
                double* __restrict__ acc) {
    const int NTOT = G_ * L_ * K_ + G_ * L_;   // 850000
    float s = 0.f;
    for (int i = blockIdx.x * 256 + threadIdx.x; i < NTOT; i += gridDim.x * 256) {
        float w = (i < G_ * L_ * K_) ? lw[i] : rw[i - G_ * L_ * K_];
        // -0.5*(w/0.1)^2 - log(0.1) - 0.5*log(2pi)
        s += fmaf(-50.f * w, w, 1.3836465597893733f);
    }
    s = block_sum_256(s);
    if (threadIdx.x == 0) atomicAdd(acc, -(double)s);
}

// --- 7. fused decoder: mixture + Poisson likelihood per (c,g) --------------
// grid (1000 genes, 4 cell-tiles) x 256 threads
__global__ __launch_bounds__(256)
void main_kernel(const float* __restrict__ latT,      // [50][1024]
                 const unsigned int* __restrict__ hist,
                 const unsigned int* __restrict__ frag,
                 const float* __restrict__ lw,        // [1000][50][16]
                 const float* __restrict__ rw,        // [1000][50]
                 const float* __restrict__ baseline,  // [1000][16]
                 const float* __restrict__ rho_bias,  // [1000]
                 const int* __restrict__ libsize,
                 double* __restrict__ acc) {
    int g = blockIdx.x;
    int c = blockIdx.y * 256 + threadIdx.x;
    const float* lwg = lw + (size_t)g * (L_ * K_);   // wave-uniform base
    const float* rwg = rw + (size_t)g * L_;
    float logits[K_];
#pragma unroll
    for (int k = 0; k < K_; ++k) logits[k] = baseline[g * K_ + k];
    float rho = 0.f;
    for (int l = 0; l < L_; ++l) {
        float lv = latT[(size_t)l * C_ + c];         // coalesced
        rho = fmaf(lv, rwg[l], rho);
#pragma unroll
        for (int k = 0; k < K_; ++k)
            logits[k] = fmaf(lv, lwg[l * K_ + k], logits[k]);  // s_load operand
    }
    float m = logits[0];
#pragma unroll
    for (int k = 1; k < K_; ++k) m = fmaxf(m, logits[k]);
    float se = 0.f;
#pragma unroll
    for (int k = 0; k < K_; ++k) se += __expf(logits[k] - m);
    float lse = m + __logf(se);
    float mix = 0.f;
#pragma unroll
    for (int k = 0; k < K_; ++k) {
        float cnt = (float)hist[(size_t)(g * K_ + k) * C_ + c];  // coalesced
        mix = fmaf(cnt, logits[k] - lse, mix);
    }
    float fc = (float)frag[(size_t)g * C_ + c];
    float fe = rho_bias[g] * __expf(rho) * (float)libsize[c];
    float lf = fmaf(fc, __logf(fe), -fe) - lgammaf(fc + 1.0f);
    float v = -(CUT_SCALE * mix + CELL_SCALE * lf);
    float s = block_sum_256(v);
    if (threadIdx.x == 0) atomicAdd(acc, (double)s);
}

// --- 8. finalize -----------------------------------------------------------
__global__ void final_kernel(const double* __restrict__ acc, float* __restrict__ out) {
    // -CUT_SCALE_total * log(16): 12.5 * 4e6 * log(16)
    out[0] = (float)(acc[0] - 138629436.11198905);
}

extern "C" void kernel_launch(void* const* d_in, const int* in_sizes, int n_in,
                              void* d_out, int out_size, void* d_ws, size_t ws_size,
                              hipStream_t stream) {
    const float* cut_coord = (const float*)d_in[0];
    const float* eps       = (const float*)d_in[1];
    const float* enc_W1    = (const float*)d_in[2];
    // d_in[3] = enc_b1 : cancels through BatchNorm, unused
    const float* bn_gamma  = (const float*)d_in[4];
    const float* bn_beta   = (const float*)d_in[5];
    const float* W_loc     = (const float*)d_in[6];
    const float* b_loc     = (const float*)d_in[7];
    const float* W_scale   = (const float*)d_in[8];
    const float* b_scale   = (const float*)d_in[9];
    const float* logit_w   = (const float*)d_in[10];
    const float* rho_w     = (const float*)d_in[11];
    const float* baseline  = (const float*)d_in[12];
    const float* rho_bias  = (const float*)d_in[13];
    const int* cut_cxg     = (const int*)d_in[14];
    // d_in[15] = cut_local_gene_ix : derivable from cxg, unused
    const int* frag_ix     = (const int*)d_in[16];
    // d_in[17] genes_oi, d_in[18] cells_oi : identity, unused
    const int* libsize     = (const int*)d_in[19];

    char* ws = (char*)d_ws;
    unsigned int* hist = (unsigned int*)(ws + HIST_OFF);
    unsigned int* frag = (unsigned int*)(ws + FRAG_OFF);
    float* hT   = (float*)(ws + H_OFF);
    float* bn   = (float*)(ws + BN_OFF);
    float* latT = (float*)(ws + LATT_OFF);
    double* acc = (double*)(ws + ACC_OFF);
    float* out  = (float*)d_out;

    int n_cuts  = in_sizes[0];
    int n_frags = in_sizes[16];

    hipMemsetAsync(d_ws, 0, WS_BYTES, stream);

    hist_kernel<<<(n_cuts + 255) / 256, 256, 0, stream>>>(cut_coord, cut_cxg, hist, n_cuts);
    frag_kernel<<<(n_frags + 255) / 256, 256, 0, stream>>>(frag_ix, frag, n_frags);
    enc_kernel<<<250, 256, 0, stream>>>(hist, enc_W1, hT);
    bn_kernel<<<NHID_, 256, 0, stream>>>(hT, bn_gamma, bn_beta, bn);
    latent_kernel<<<(C_ * L_ + 255) / 256, 256, 0, stream>>>(
        hT, bn, W_loc, b_loc, W_scale, b_scale, eps, latT, acc);
    wkl_kernel<<<512, 256, 0, stream>>>(logit_w, rho_w, acc);
    main_kernel<<<dim3(G_, 4), 256, 0, stream>>>(
        latT, hist, frag, logit_w, rho_w, baseline, rho_bias, libsize, acc);
    final_kernel<<<1, 1, 0, stream>>>(acc, out);
}